// Round 13
// baseline (685.364 us; speedup 1.0000x reference)
//
#include <hip/hip_runtime.h>
#include <math.h>

#define HIDDEN 64
#define N_LAYERS 4
#define N_CLASSES 10
#define N_GRAPHS 512
#define BSH 8                        // coarse bucket: 256 nodes
#define NPB 256                      // nodes per bucket
#define PART_K 2048                  // edges per partition block

typedef __attribute__((ext_vector_type(8))) short short8;    // 8 bf16 (4 VGPRs)
typedef __attribute__((ext_vector_type(4))) float f32x4;     // MFMA acc

// ---------------- pass 1: global bucket histogram ----------------
__global__ __launch_bounds__(256) void k_histA(const int* __restrict__ dst,
                                               int* __restrict__ ghist, int E, int NB) {
    __shared__ int hist[512];
    int t = threadIdx.x;
    hist[t] = 0; hist[t + 256] = 0;
    __syncthreads();
    int base = blockIdx.x * PART_K;
    int kend = min(PART_K, E - base);
    for (int k = t; k < kend; k += 256) atomicAdd(&hist[dst[base + k] >> BSH], 1);
    __syncthreads();
    for (int j = t; j < NB; j += 256) {
        int h = hist[j];
        if (h) atomicAdd(&ghist[j], h);
    }
}

// ---------------- pass 2: scan bucket sizes -> bases, init cursors ----------------
__global__ __launch_bounds__(256) void k_bucketscan(const int* __restrict__ ghist,
                                                    int* __restrict__ bucketbase,
                                                    int* __restrict__ gcur, int NB) {
    __shared__ int s[256];
    int t = threadIdx.x;
    int j0 = 2 * t, j1 = 2 * t + 1;
    int h0 = (j0 < NB) ? ghist[j0] : 0;
    int h1 = (j1 < NB) ? ghist[j1] : 0;
    s[t] = h0 + h1; __syncthreads();
    for (int o = 1; o < 256; o <<= 1) {
        int x = (t >= o) ? s[t - o] : 0;
        __syncthreads();
        s[t] += x;
        __syncthreads();
    }
    int base = (t == 0) ? 0 : s[t - 1];
    if (j0 <= NB) { bucketbase[j0] = base;      gcur[j0] = base; }
    if (j1 <= NB) { bucketbase[j1] = base + h0; gcur[j1] = base + h0; }
}

// ---------------- pass 3: partition edges into bucket segments (LDS reorder) ----------------
__global__ __launch_bounds__(256) void k_partition(const int* __restrict__ src,
                                                   const int* __restrict__ dst,
                                                   int* __restrict__ gcur,
                                                   int* __restrict__ packed,
                                                   int E, int NB) {
    __shared__ int hist[512];
    __shared__ int scanE[512];
    __shared__ int cur[512];
    __shared__ int delta[512];
    __shared__ int ps[256];
    __shared__ int stage[PART_K];
    int t = threadIdx.x;
    int base = blockIdx.x * PART_K;
    int kend = min(PART_K, E - base);

    hist[t] = 0; hist[t + 256] = 0;
    __syncthreads();
    for (int k = t; k < kend; k += 256) atomicAdd(&hist[dst[base + k] >> BSH], 1);
    __syncthreads();

    int j0 = 2 * t, j1 = j0 + 1;
    int h0 = hist[j0], h1 = hist[j1];
    ps[t] = h0 + h1; __syncthreads();
    for (int o = 1; o < 256; o <<= 1) {
        int x = (t >= o) ? ps[t - o] : 0;
        __syncthreads();
        ps[t] += x;
        __syncthreads();
    }
    int bexc = (t == 0) ? 0 : ps[t - 1];
    scanE[j0] = bexc;
    scanE[j1] = bexc + h0;
    __syncthreads();

    for (int j = t; j < NB; j += 256) {
        int h = hist[j];
        int g = h ? atomicAdd(&gcur[j], h) : 0;
        delta[j] = g - scanE[j];
        cur[j]   = scanE[j];
    }
    __syncthreads();

    for (int k = t; k < kend; k += 256) {
        int d = dst[base + k], s = src[base + k];
        int j = d >> BSH;
        int pos = atomicAdd(&cur[j], 1);
        stage[pos] = (s << BSH) | (d & (NPB - 1));
    }
    __syncthreads();

    for (int i = t; i < kend; i += 256) {
        int lo = 0, hi = NB;
        while (hi - lo > 1) {
            int mid = (lo + hi) >> 1;
            if (scanE[mid] <= i) lo = mid; else hi = mid;
        }
        packed[i + delta[lo]] = stage[i];
    }
}

// ---------------- pass 4: per-bucket CSR fill; emits rowptr + dis ----------------
__global__ __launch_bounds__(256) void k_fill3(const int* __restrict__ packed,
                                               const int* __restrict__ bucketbase,
                                               int* __restrict__ rowptr,
                                               float* __restrict__ dis,
                                               int* __restrict__ csr_src,
                                               int N, int E) {
    __shared__ int cnt[256];
    __shared__ int rp[256];
    int j = blockIdx.x;
    int t = threadIdx.x;
    int node0 = j << BSH;
    int segb = bucketbase[j];
    int sege = bucketbase[j + 1];

    cnt[t] = 0; __syncthreads();
    for (int i = segb + t; i < sege; i += 256) atomicAdd(&cnt[packed[i] & (NPB - 1)], 1);
    __syncthreads();

    int c = cnt[t];
    rp[t] = c; __syncthreads();
    for (int o = 1; o < 256; o <<= 1) {
        int x = (t >= o) ? rp[t - o] : 0;
        __syncthreads();
        rp[t] += x;
        __syncthreads();
    }
    int start = segb + rp[t] - c;
    int node = node0 + t;
    if (node < N) {
        rowptr[node] = start;
        dis[node] = rsqrtf((float)c + 1.0f);
        if (node == N - 1) rowptr[N] = E;
    }
    __syncthreads();
    cnt[t] = start;
    __syncthreads();
    for (int i = segb + t; i < sege; i += 256) {
        int v = packed[i];
        int slot = atomicAdd(&cnt[v & (NPB - 1)], 1);
        csr_src[slot] = v >> BSH;
    }
}

// ---------------- bf16 helpers ----------------
__device__ __forceinline__ unsigned short f2bf(float f) {
    unsigned int u = __float_as_uint(f);
    u += 0x7fffu + ((u >> 16) & 1u);          // RNE
    return (unsigned short)(u >> 16);
}
__device__ __forceinline__ void bf4_decode(uint2 rv, float* f) {
    f[0] = __uint_as_float(rv.x << 16); f[1] = __uint_as_float(rv.x & 0xffff0000u);
    f[2] = __uint_as_float(rv.y << 16); f[3] = __uint_as_float(rv.y & 0xffff0000u);
}

// ---------------- prep: weight matrix -> bf16 B-fragment layout ----------------
__global__ __launch_bounds__(256) void k_prepW(const float* __restrict__ W,
                                               unsigned short* __restrict__ Wb) {
    int idx = blockIdx.x * 256 + threadIdx.x;        // l*4096 + k*64 + n
    int l = idx >> 12;
    int kn = idx & 4095;
    int k = kn >> 6, n = kn & 63;
    int nt = n >> 4, nl = n & 15;
    int kt = k >> 5, kr = k & 31;
    int quad = kr >> 3, j = kr & 7;
    int lane = quad * 16 + nl;
    int pos = (((nt * 2 + kt) * 64 + lane) << 3) + j;
    Wb[(l << 12) + pos] = f2bf(W[(size_t)l * 4096 + k * 64 + n]);
}

// ---------------- cast x (fp32) -> bf16 SLAB layout ----------------
// slab s holds features [s*16, s*16+16) for all nodes: xb[s*N*16 + node*16 + f]
__global__ __launch_bounds__(256) void k_castx(const float* __restrict__ x,
                                               unsigned short* __restrict__ xb, int N) {
    int i = blockIdx.x * 256 + threadIdx.x;          // over N*16 ushort4 chunks
    if (i < N * 16) {
        int node = i >> 4, chunk = i & 15;
        float4 v = ((const float4*)x)[i];
        ushort4 o;
        o.x = f2bf(v.x); o.y = f2bf(v.y); o.z = f2bf(v.z); o.w = f2bf(v.w);
        size_t slabN = (size_t)N * 16;
        *(ushort4*)(xb + (size_t)(chunk >> 2) * slabN + (size_t)node * 16 + (chunk & 3) * 4) = o;
    }
}

// ---------------- gather, slab-sliced + XCD-affine ----------------
// slice = blockIdx & 3 -> slab of 16 features (32 B/node, 3.2 MB/slab fits XCD L2).
// wave = one node-slice; 16 edge-groups x 4 lanes x 8 B (uint2).
__global__ __launch_bounds__(256) void k_gather(const int* __restrict__ csr_src,
                                                const int* __restrict__ rowptr,
                                                const float* __restrict__ dis,
                                                const unsigned short* __restrict__ Gb,
                                                unsigned short* __restrict__ AGGb, int N) {
    int slice = blockIdx.x & 3;
    int node  = (blockIdx.x >> 2) * 4 + (threadIdx.x >> 6);
    if (node >= N) return;
    int lane = threadIdx.x & 63;
    int grp  = lane >> 2;      // 0..15 edge groups
    int f2   = lane & 3;       // uint2 (4 bf16) within the 32-B slab row
    size_t slabN = (size_t)N * 16;
    const unsigned short* slab = Gb + (size_t)slice * slabN;
    int beg = rowptr[node];
    int end = rowptr[node + 1];

    float a[4] = {0.f, 0.f, 0.f, 0.f};
    for (int e = beg + grp; e < end; e += 16) {
        int s0 = csr_src[e];
        uint2 rv = *(const uint2*)(slab + (size_t)s0 * 16 + f2 * 4);
        float f[4]; bf4_decode(rv, f);
        a[0] += f[0]; a[1] += f[1]; a[2] += f[2]; a[3] += f[3];
    }
    #pragma unroll
    for (int j = 0; j < 4; ++j) {
        a[j] += __shfl_xor(a[j], 4);
        a[j] += __shfl_xor(a[j], 8);
        a[j] += __shfl_xor(a[j], 16);
        a[j] += __shfl_xor(a[j], 32);
    }
    if (grp == 0) {
        uint2 sv = *(const uint2*)(slab + (size_t)node * 16 + f2 * 4);
        float sf[4]; bf4_decode(sv, sf);
        float dd = dis[node];
        unsigned int w0 = f2bf(dd * (a[0] + sf[0]));
        unsigned int w1 = f2bf(dd * (a[1] + sf[1]));
        unsigned int w2 = f2bf(dd * (a[2] + sf[2]));
        unsigned int w3 = f2bf(dd * (a[3] + sf[3]));
        uint2 o;
        o.x = w0 | (w1 << 16);
        o.y = w2 | (w3 << 16);
        *(uint2*)(AGGb + (size_t)slice * slabN + (size_t)node * 16 + f2 * 4) = o;
    }
}

// ---------------- MFMA GEMM over slab-layout input, 32 rows/wave ----------------
// mode 0 (enc):  Gbo = bf16( dis * (v + b) )
// mode 1 (mid):  Gbo = bf16( dis * silu(v + b) )
// mode 2 (last): pooled[batch] += silu(v + b)
__global__ __launch_bounds__(256) void k_gemm_mfma(const unsigned short* __restrict__ in,
                                                   const unsigned short* __restrict__ Wb,
                                                   const float* __restrict__ bias,
                                                   const float* __restrict__ dis,
                                                   const int* __restrict__ batch,
                                                   unsigned short* __restrict__ Gbo,
                                                   float* __restrict__ pooled,
                                                   int N, int mode) {
    int wave = threadIdx.x >> 6;
    int lane = threadIdx.x & 63;
    int row0 = (blockIdx.x * 4 + wave) * 32;
    if (row0 >= N) return;
    int quad = lane >> 4, nl = lane & 15;
    size_t slabN = (size_t)N * 16;
    int s0 = quad >> 1;                 // slab of a0 features (0..1)
    int o0 = (quad & 1) * 8;            // offset within slab row

    short8 bf[4][2];
    #pragma unroll
    for (int nt = 0; nt < 4; ++nt)
        #pragma unroll
        for (int kt = 0; kt < 2; ++kt)
            bf[nt][kt] = *(const short8*)(Wb + (((nt * 2 + kt) * 64 + lane) << 3));

    f32x4 acc[2][4];
    #pragma unroll
    for (int h = 0; h < 2; ++h) {
        int r = row0 + h * 16 + nl; if (r >= N) r = N - 1;
        short8 a0 = *(const short8*)(in + (size_t)s0 * slabN + (size_t)r * 16 + o0);
        short8 a1 = *(const short8*)(in + (size_t)(s0 + 2) * slabN + (size_t)r * 16 + o0);
        #pragma unroll
        for (int nt = 0; nt < 4; ++nt) {
            acc[h][nt] = (f32x4){0.f, 0.f, 0.f, 0.f};
            acc[h][nt] = __builtin_amdgcn_mfma_f32_16x16x32_bf16(a0, bf[nt][0], acc[h][nt], 0, 0, 0);
            acc[h][nt] = __builtin_amdgcn_mfma_f32_16x16x32_bf16(a1, bf[nt][1], acc[h][nt], 0, 0, 0);
        }
    }

    float b[4];
    #pragma unroll
    for (int nt = 0; nt < 4; ++nt) b[nt] = bias[nt * 16 + nl];

    if (mode != 2) {
        #pragma unroll
        for (int h = 0; h < 2; ++h) {
            #pragma unroll
            for (int reg = 0; reg < 4; ++reg) {
                int rr = row0 + h * 16 + quad * 4 + reg;
                if (rr < N) {
                    float ds = dis[rr];
                    #pragma unroll
                    for (int nt = 0; nt < 4; ++nt) {
                        float v = acc[h][nt][reg] + b[nt];
                        if (mode == 1) v = v / (1.0f + expf(-v));
                        Gbo[(size_t)nt * slabN + (size_t)rr * 16 + nl] = f2bf(ds * v);
                    }
                }
            }
        }
    } else {
        float run[4] = {0.f, 0.f, 0.f, 0.f};
        int cur = -1;
        #pragma unroll
        for (int h = 0; h < 2; ++h) {
            #pragma unroll
            for (int reg = 0; reg < 4; ++reg) {
                int rr = row0 + h * 16 + quad * 4 + reg;
                if (rr < N) {
                    int bi = batch[rr];
                    float vals[4];
                    #pragma unroll
                    for (int nt = 0; nt < 4; ++nt) {
                        float v = acc[h][nt][reg] + b[nt];
                        vals[nt] = v / (1.0f + expf(-v));
                    }
                    if (bi != cur) {
                        if (cur >= 0) {
                            #pragma unroll
                            for (int nt = 0; nt < 4; ++nt)
                                atomicAdd(&pooled[cur * 64 + nt * 16 + nl], run[nt]);
                        }
                        cur = bi;
                        #pragma unroll
                        for (int nt = 0; nt < 4; ++nt) run[nt] = vals[nt];
                    } else {
                        #pragma unroll
                        for (int nt = 0; nt < 4; ++nt) run[nt] += vals[nt];
                    }
                }
            }
        }
        if (cur >= 0) {
            #pragma unroll
            for (int nt = 0; nt < 4; ++nt)
                atomicAdd(&pooled[cur * 64 + nt * 16 + nl], run[nt]);
        }
    }
}

// ---------------- readout ----------------
__global__ __launch_bounds__(256) void k_readout(const float* __restrict__ pooled,
                                                 const float* __restrict__ Wout,
                                                 const float* __restrict__ bout,
                                                 float* __restrict__ out) {
    int idx = blockIdx.x * 256 + threadIdx.x;
    if (idx >= N_GRAPHS * N_CLASSES) return;
    int g = idx / N_CLASSES, c = idx % N_CLASSES;
    float s = bout[c];
    #pragma unroll
    for (int j = 0; j < 64; ++j) s += pooled[g * 64 + j] * Wout[j * N_CLASSES + c];
    out[idx] = fmaxf(s, 0.0f);
}

extern "C" void kernel_launch(void* const* d_in, const int* in_sizes, int n_in,
                              void* d_out, int out_size, void* d_ws, size_t ws_size,
                              hipStream_t stream) {
    const float* x      = (const float*)d_in[0];
    const int*   ei     = (const int*)d_in[1];
    const int*   batch  = (const int*)d_in[2];
    const float* W_enc  = (const float*)d_in[3];
    const float* b_enc  = (const float*)d_in[4];
    const float* W_conv = (const float*)d_in[5];
    const float* b_conv = (const float*)d_in[6];
    const float* W_out  = (const float*)d_in[7];
    const float* b_out  = (const float*)d_in[8];
    float* out = (float*)d_out;

    const int N = in_sizes[2];
    const int E = in_sizes[1] / 2;
    const int* src = ei;
    const int* dst = ei + E;
    const int NB   = (N + NPB - 1) >> BSH;
    const int NBLK = (E + PART_K - 1) / PART_K;

    char* ws = (char*)d_ws;
    size_t off = 0;
    auto alloc = [&](size_t bytes) -> char* {
        char* p = ws + off;
        off += (bytes + 255) & ~(size_t)255;
        return p;
    };
    int*   ghist      = (int*)alloc((size_t)(NB + 1) * sizeof(int));
    int*   bucketbase = (int*)alloc((size_t)(NB + 1) * sizeof(int));
    int*   gcur       = (int*)alloc((size_t)(NB + 1) * sizeof(int));
    int*   packed     = (int*)alloc((size_t)E * sizeof(int));
    int*   csr_src    = (int*)alloc((size_t)E * sizeof(int));
    int*   rowptr     = (int*)alloc((size_t)(N + 1) * sizeof(int));
    float* dis        = (float*)alloc((size_t)N * sizeof(float));
    unsigned short* xb   = (unsigned short*)alloc((size_t)N * HIDDEN * sizeof(unsigned short));
    unsigned short* GbA  = (unsigned short*)alloc((size_t)N * HIDDEN * sizeof(unsigned short));
    unsigned short* AGGb = (unsigned short*)alloc((size_t)N * HIDDEN * sizeof(unsigned short));
    unsigned short* Wb   = (unsigned short*)alloc((size_t)(N_LAYERS + 1) * 4096 * sizeof(unsigned short));
    float* pooled     = (float*)alloc((size_t)N_GRAPHS * HIDDEN * sizeof(float));
    (void)ws_size;

    hipMemsetAsync(ghist, 0, (size_t)(NB + 1) * sizeof(int), stream);
    hipMemsetAsync(pooled, 0, (size_t)N_GRAPHS * HIDDEN * sizeof(float), stream);

    k_histA     <<<NBLK, 256, 0, stream>>>(dst, ghist, E, NB);
    k_bucketscan<<<1,    256, 0, stream>>>(ghist, bucketbase, gcur, NB);
    k_partition <<<NBLK, 256, 0, stream>>>(src, dst, gcur, packed, E, NB);
    k_fill3     <<<NB,   256, 0, stream>>>(packed, bucketbase, rowptr, dis, csr_src, N, E);
    k_prepW<<<(N_LAYERS * 4096) / 256, 256, 0, stream>>>(W_conv, Wb);
    k_prepW<<<4096 / 256, 256, 0, stream>>>(W_enc, Wb + (size_t)N_LAYERS * 4096);
    k_castx<<<(N * 16 + 255) / 256, 256, 0, stream>>>(x, xb, N);

    int gb32 = (N + 127) / 128;   // 32 rows/wave, 4 waves/block
    // encoder: GbA = bf16(dis * (xb @ W_enc + b_enc))
    k_gemm_mfma<<<gb32, 256, 0, stream>>>(xb, Wb + (size_t)N_LAYERS * 4096, b_enc,
                                          dis, batch, GbA, pooled, N, 0);

    int gather_blocks = ((N + 3) / 4) * 4;   // x4 slices
    for (int l = 0; l < N_LAYERS; ++l) {
        int last = (l == N_LAYERS - 1);
        k_gather<<<gather_blocks, 256, 0, stream>>>(csr_src, rowptr, dis, GbA, AGGb, N);
        k_gemm_mfma<<<gb32, 256, 0, stream>>>(AGGb, Wb + (size_t)l * 4096,
                                              b_conv + (size_t)l * HIDDEN, dis, batch,
                                              GbA, pooled, N, last ? 2 : 1);
    }

    k_readout<<<(N_GRAPHS * N_CLASSES + 255) / 256, 256, 0, stream>>>(pooled, W_out, b_out, out);
}

// Round 14
// 424.192 us; speedup vs baseline: 1.6157x; 1.6157x over previous
//
#include <hip/hip_runtime.h>
#include <math.h>

#define HIDDEN 64
#define N_LAYERS 4
#define N_CLASSES 10
#define N_GRAPHS 512
#define BSH 8                        // coarse bucket: 256 nodes
#define NPB 256                      // nodes per bucket
#define PART_K 2048                  // edges per partition block

typedef _Float16 __h;
typedef __attribute__((ext_vector_type(4))) _Float16 half4;   // 8 B
typedef __attribute__((ext_vector_type(8))) _Float16 half8;   // 16 B, MFMA A/B frag
typedef __attribute__((ext_vector_type(4))) float f32x4;      // MFMA acc

// ---------------- pass 1: global bucket histogram ----------------
__global__ __launch_bounds__(256) void k_histA(const int* __restrict__ dst,
                                               int* __restrict__ ghist, int E, int NB) {
    __shared__ int hist[512];
    int t = threadIdx.x;
    hist[t] = 0; hist[t + 256] = 0;
    __syncthreads();
    int base = blockIdx.x * PART_K;
    int kend = min(PART_K, E - base);
    for (int k = t; k < kend; k += 256) atomicAdd(&hist[dst[base + k] >> BSH], 1);
    __syncthreads();
    for (int j = t; j < NB; j += 256) {
        int h = hist[j];
        if (h) atomicAdd(&ghist[j], h);
    }
}

// ---------------- pass 2: scan bucket sizes -> bases, init cursors ----------------
__global__ __launch_bounds__(256) void k_bucketscan(const int* __restrict__ ghist,
                                                    int* __restrict__ bucketbase,
                                                    int* __restrict__ gcur, int NB) {
    __shared__ int s[256];
    int t = threadIdx.x;
    int j0 = 2 * t, j1 = 2 * t + 1;
    int h0 = (j0 < NB) ? ghist[j0] : 0;
    int h1 = (j1 < NB) ? ghist[j1] : 0;
    s[t] = h0 + h1; __syncthreads();
    for (int o = 1; o < 256; o <<= 1) {
        int x = (t >= o) ? s[t - o] : 0;
        __syncthreads();
        s[t] += x;
        __syncthreads();
    }
    int base = (t == 0) ? 0 : s[t - 1];
    if (j0 <= NB) { bucketbase[j0] = base;      gcur[j0] = base; }
    if (j1 <= NB) { bucketbase[j1] = base + h0; gcur[j1] = base + h0; }
}

// ---------------- pass 3: partition edges into bucket segments (LDS reorder) ----------------
__global__ __launch_bounds__(256) void k_partition(const int* __restrict__ src,
                                                   const int* __restrict__ dst,
                                                   int* __restrict__ gcur,
                                                   int* __restrict__ packed,
                                                   int E, int NB) {
    __shared__ int hist[512];
    __shared__ int scanE[512];
    __shared__ int cur[512];
    __shared__ int delta[512];
    __shared__ int ps[256];
    __shared__ int stage[PART_K];
    int t = threadIdx.x;
    int base = blockIdx.x * PART_K;
    int kend = min(PART_K, E - base);

    hist[t] = 0; hist[t + 256] = 0;
    __syncthreads();
    for (int k = t; k < kend; k += 256) atomicAdd(&hist[dst[base + k] >> BSH], 1);
    __syncthreads();

    int j0 = 2 * t, j1 = j0 + 1;
    int h0 = hist[j0], h1 = hist[j1];
    ps[t] = h0 + h1; __syncthreads();
    for (int o = 1; o < 256; o <<= 1) {
        int x = (t >= o) ? ps[t - o] : 0;
        __syncthreads();
        ps[t] += x;
        __syncthreads();
    }
    int bexc = (t == 0) ? 0 : ps[t - 1];
    scanE[j0] = bexc;
    scanE[j1] = bexc + h0;
    __syncthreads();

    for (int j = t; j < NB; j += 256) {
        int h = hist[j];
        int g = h ? atomicAdd(&gcur[j], h) : 0;
        delta[j] = g - scanE[j];
        cur[j]   = scanE[j];
    }
    __syncthreads();

    for (int k = t; k < kend; k += 256) {
        int d = dst[base + k], s = src[base + k];
        int j = d >> BSH;
        int pos = atomicAdd(&cur[j], 1);
        stage[pos] = (s << BSH) | (d & (NPB - 1));
    }
    __syncthreads();

    for (int i = t; i < kend; i += 256) {
        int lo = 0, hi = NB;
        while (hi - lo > 1) {
            int mid = (lo + hi) >> 1;
            if (scanE[mid] <= i) lo = mid; else hi = mid;
        }
        packed[i + delta[lo]] = stage[i];
    }
}

// ---------------- pass 4: per-bucket CSR fill; emits rowptr + dis ----------------
__global__ __launch_bounds__(256) void k_fill3(const int* __restrict__ packed,
                                               const int* __restrict__ bucketbase,
                                               int* __restrict__ rowptr,
                                               float* __restrict__ dis,
                                               int* __restrict__ csr_src,
                                               int N, int E) {
    __shared__ int cnt[256];
    __shared__ int rp[256];
    int j = blockIdx.x;
    int t = threadIdx.x;
    int node0 = j << BSH;
    int segb = bucketbase[j];
    int sege = bucketbase[j + 1];

    cnt[t] = 0; __syncthreads();
    for (int i = segb + t; i < sege; i += 256) atomicAdd(&cnt[packed[i] & (NPB - 1)], 1);
    __syncthreads();

    int c = cnt[t];
    rp[t] = c; __syncthreads();
    for (int o = 1; o < 256; o <<= 1) {
        int x = (t >= o) ? rp[t - o] : 0;
        __syncthreads();
        rp[t] += x;
        __syncthreads();
    }
    int start = segb + rp[t] - c;
    int node = node0 + t;
    if (node < N) {
        rowptr[node] = start;
        dis[node] = rsqrtf((float)c + 1.0f);
        if (node == N - 1) rowptr[N] = E;
    }
    __syncthreads();
    cnt[t] = start;
    __syncthreads();
    for (int i = segb + t; i < sege; i += 256) {
        int v = packed[i];
        int slot = atomicAdd(&cnt[v & (NPB - 1)], 1);
        csr_src[slot] = v >> BSH;
    }
}

// ---------------- fp16 helpers ----------------
__device__ __forceinline__ half4 shfl_xor_h4(half4 v, int m) {
    uint2 u = __builtin_bit_cast(uint2, v);
    u.x = __shfl_xor((int)u.x, m);
    u.y = __shfl_xor((int)u.y, m);
    return __builtin_bit_cast(half4, u);
}

// ---------------- prep: W_conv (l=0..3) + W_enc (l=4) -> fp16 B-fragment layout ----------------
__global__ __launch_bounds__(256) void k_prepW(const float* __restrict__ Wconv,
                                               const float* __restrict__ Wenc,
                                               __h* __restrict__ Wh) {
    int idx = blockIdx.x * 256 + threadIdx.x;        // l*4096 + k*64 + n
    int l = idx >> 12;
    int kn = idx & 4095;
    int k = kn >> 6, n = kn & 63;
    int nt = n >> 4, nl = n & 15;
    int kt = k >> 5, kr = k & 31;
    int quad = kr >> 3, j = kr & 7;
    int lane = quad * 16 + nl;
    int pos = (((nt * 2 + kt) * 64 + lane) << 3) + j;
    float w = (l < N_LAYERS) ? Wconv[(size_t)l * 4096 + kn] : Wenc[kn];
    Wh[(l << 12) + pos] = (__h)w;
}

// ---------------- cast x (fp32) -> fp16 rows ----------------
__global__ __launch_bounds__(256) void k_castx(const float* __restrict__ x,
                                               __h* __restrict__ xh, int n4) {
    int i = blockIdx.x * 256 + threadIdx.x;          // over float4 chunks
    if (i < n4) {
        float4 v = ((const float4*)x)[i];
        half4 o = {(__h)v.x, (__h)v.y, (__h)v.z, (__h)v.w};
        ((half4*)xh)[i] = o;
    }
}

// ---------------- gather: AGG[d] = fp16( dis[d] * (G[d] + sum G[src]) ) ----------------
// one wave per node; 4 edge-groups x 16 lanes x 8B(half4); 2-edge unroll; packed fp16 adds.
__global__ __launch_bounds__(256) void k_gather(const int* __restrict__ csr_src,
                                                const int* __restrict__ rowptr,
                                                const float* __restrict__ dis,
                                                const __h* __restrict__ G,
                                                __h* __restrict__ AGG, int N) {
    int node = blockIdx.x * 4 + (threadIdx.x >> 6);
    if (node >= N) return;
    int lane = threadIdx.x & 63;
    int grp  = lane >> 4;      // 0..3 edge groups
    int f4   = lane & 15;      // 8-byte (4 fp16) chunk of the 128-B row
    int beg  = rowptr[node];
    int end  = rowptr[node + 1];

    half4 a = {(__h)0.f, (__h)0.f, (__h)0.f, (__h)0.f};
    int e = beg + grp;
    while (e < end) {
        int s0 = csr_src[e];
        int e2 = e + 4;
        int s1 = (e2 < end) ? csr_src[e2] : -1;
        half4 r0 = ((const half4*)(G + (size_t)s0 * 64))[f4];
        half4 r1 = {(__h)0.f, (__h)0.f, (__h)0.f, (__h)0.f};
        if (s1 >= 0) r1 = ((const half4*)(G + (size_t)s1 * 64))[f4];
        a += r0;           // v_pk_add_f16 x2
        a += r1;
        e += 8;
    }
    a += shfl_xor_h4(a, 16);
    a += shfl_xor_h4(a, 32);

    if (grp == 0) {
        half4 self = ((const half4*)(G + (size_t)node * 64))[f4];
        __h dd = (__h)dis[node];
        half4 o = (a + self) * dd;      // packed mul
        ((half4*)(AGG + (size_t)node * 64))[f4] = o;
    }
}

// ---------------- MFMA GEMM: [N,64]fp16 @ [64,64]fp16, 32 rows/wave ----------------
// mode 0 (enc):  Gho = fp16( dis * (v + b) )
// mode 1 (mid):  Gho = fp16( dis * silu(v + b) )
// mode 2 (last): pooled[batch] += silu(v + b)
__global__ __launch_bounds__(256) void k_gemm_mfma(const __h* __restrict__ in,
                                                   const __h* __restrict__ Wh,
                                                   const float* __restrict__ bias,
                                                   const float* __restrict__ dis,
                                                   const int* __restrict__ batch,
                                                   __h* __restrict__ Gho,
                                                   float* __restrict__ pooled,
                                                   int N, int mode) {
    int wave = threadIdx.x >> 6;
    int lane = threadIdx.x & 63;
    int row0 = (blockIdx.x * 4 + wave) * 32;
    if (row0 >= N) return;
    int quad = lane >> 4, nl = lane & 15;

    half8 bf[4][2];
    #pragma unroll
    for (int nt = 0; nt < 4; ++nt)
        #pragma unroll
        for (int kt = 0; kt < 2; ++kt)
            bf[nt][kt] = *(const half8*)(Wh + (((nt * 2 + kt) * 64 + lane) << 3));

    f32x4 acc[2][4];
    #pragma unroll
    for (int h = 0; h < 2; ++h) {
        int r = row0 + h * 16 + nl; if (r >= N) r = N - 1;
        const __h* ap = in + (size_t)r * 64 + quad * 8;
        half8 a0 = *(const half8*)(ap);
        half8 a1 = *(const half8*)(ap + 32);
        #pragma unroll
        for (int nt = 0; nt < 4; ++nt) {
            acc[h][nt] = (f32x4){0.f, 0.f, 0.f, 0.f};
            acc[h][nt] = __builtin_amdgcn_mfma_f32_16x16x32_f16(a0, bf[nt][0], acc[h][nt], 0, 0, 0);
            acc[h][nt] = __builtin_amdgcn_mfma_f32_16x16x32_f16(a1, bf[nt][1], acc[h][nt], 0, 0, 0);
        }
    }

    float b[4];
    #pragma unroll
    for (int nt = 0; nt < 4; ++nt) b[nt] = bias[nt * 16 + nl];

    if (mode != 2) {
        #pragma unroll
        for (int h = 0; h < 2; ++h) {
            #pragma unroll
            for (int reg = 0; reg < 4; ++reg) {
                int rr = row0 + h * 16 + quad * 4 + reg;
                if (rr < N) {
                    float ds = dis[rr];
                    #pragma unroll
                    for (int nt = 0; nt < 4; ++nt) {
                        float v = acc[h][nt][reg] + b[nt];
                        if (mode == 1) v = v / (1.0f + expf(-v));
                        Gho[(size_t)rr * 64 + nt * 16 + nl] = (__h)(ds * v);
                    }
                }
            }
        }
    } else {
        float run[4] = {0.f, 0.f, 0.f, 0.f};
        int cur = -1;
        #pragma unroll
        for (int h = 0; h < 2; ++h) {
            #pragma unroll
            for (int reg = 0; reg < 4; ++reg) {
                int rr = row0 + h * 16 + quad * 4 + reg;
                if (rr < N) {
                    int bi = batch[rr];
                    float vals[4];
                    #pragma unroll
                    for (int nt = 0; nt < 4; ++nt) {
                        float v = acc[h][nt][reg] + b[nt];
                        vals[nt] = v / (1.0f + expf(-v));
                    }
                    if (bi != cur) {
                        if (cur >= 0) {
                            #pragma unroll
                            for (int nt = 0; nt < 4; ++nt)
                                atomicAdd(&pooled[cur * 64 + nt * 16 + nl], run[nt]);
                        }
                        cur = bi;
                        #pragma unroll
                        for (int nt = 0; nt < 4; ++nt) run[nt] = vals[nt];
                    } else {
                        #pragma unroll
                        for (int nt = 0; nt < 4; ++nt) run[nt] += vals[nt];
                    }
                }
            }
        }
        if (cur >= 0) {
            #pragma unroll
            for (int nt = 0; nt < 4; ++nt)
                atomicAdd(&pooled[cur * 64 + nt * 16 + nl], run[nt]);
        }
    }
}

// ---------------- readout ----------------
__global__ __launch_bounds__(256) void k_readout(const float* __restrict__ pooled,
                                                 const float* __restrict__ Wout,
                                                 const float* __restrict__ bout,
                                                 float* __restrict__ out) {
    int idx = blockIdx.x * 256 + threadIdx.x;
    if (idx >= N_GRAPHS * N_CLASSES) return;
    int g = idx / N_CLASSES, c = idx % N_CLASSES;
    float s = bout[c];
    #pragma unroll
    for (int j = 0; j < 64; ++j) s += pooled[g * 64 + j] * Wout[j * N_CLASSES + c];
    out[idx] = fmaxf(s, 0.0f);
}

extern "C" void kernel_launch(void* const* d_in, const int* in_sizes, int n_in,
                              void* d_out, int out_size, void* d_ws, size_t ws_size,
                              hipStream_t stream) {
    const float* x      = (const float*)d_in[0];
    const int*   ei     = (const int*)d_in[1];
    const int*   batch  = (const int*)d_in[2];
    const float* W_enc  = (const float*)d_in[3];
    const float* b_enc  = (const float*)d_in[4];
    const float* W_conv = (const float*)d_in[5];
    const float* b_conv = (const float*)d_in[6];
    const float* W_out  = (const float*)d_in[7];
    const float* b_out  = (const float*)d_in[8];
    float* out = (float*)d_out;

    const int N = in_sizes[2];
    const int E = in_sizes[1] / 2;
    const int* src = ei;
    const int* dst = ei + E;
    const int NB   = (N + NPB - 1) >> BSH;
    const int NBLK = (E + PART_K - 1) / PART_K;

    char* ws = (char*)d_ws;
    size_t off = 0;
    auto alloc = [&](size_t bytes) -> char* {
        char* p = ws + off;
        off += (bytes + 255) & ~(size_t)255;
        return p;
    };
    int*   ghist      = (int*)alloc((size_t)(NB + 1) * sizeof(int));
    int*   bucketbase = (int*)alloc((size_t)(NB + 1) * sizeof(int));
    int*   gcur       = (int*)alloc((size_t)(NB + 1) * sizeof(int));
    int*   packed     = (int*)alloc((size_t)E * sizeof(int));
    int*   csr_src    = (int*)alloc((size_t)E * sizeof(int));
    int*   rowptr     = (int*)alloc((size_t)(N + 1) * sizeof(int));
    float* dis        = (float*)alloc((size_t)N * sizeof(float));
    __h*   xh         = (__h*)alloc((size_t)N * HIDDEN * sizeof(__h));
    __h*   GhA        = (__h*)alloc((size_t)N * HIDDEN * sizeof(__h));
    __h*   AGGh       = (__h*)alloc((size_t)N * HIDDEN * sizeof(__h));
    __h*   Wh         = (__h*)alloc((size_t)(N_LAYERS + 1) * 4096 * sizeof(__h));
    float* pooled     = (float*)alloc((size_t)N_GRAPHS * HIDDEN * sizeof(float));
    (void)ws_size;

    hipMemsetAsync(ghist, 0, (size_t)(NB + 1) * sizeof(int), stream);
    hipMemsetAsync(pooled, 0, (size_t)N_GRAPHS * HIDDEN * sizeof(float), stream);

    k_histA     <<<NBLK, 256, 0, stream>>>(dst, ghist, E, NB);
    k_bucketscan<<<1,    256, 0, stream>>>(ghist, bucketbase, gcur, NB);
    k_partition <<<NBLK, 256, 0, stream>>>(src, dst, gcur, packed, E, NB);
    k_fill3     <<<NB,   256, 0, stream>>>(packed, bucketbase, rowptr, dis, csr_src, N, E);
    k_prepW<<<((N_LAYERS + 1) * 4096) / 256, 256, 0, stream>>>(W_conv, W_enc, Wh);
    k_castx<<<(N * 16 + 255) / 256, 256, 0, stream>>>(x, xh, N * 16);

    int gb32 = (N + 127) / 128;   // 32 rows/wave, 4 waves/block
    // encoder: GhA = fp16(dis * (xh @ W_enc + b_enc))
    k_gemm_mfma<<<gb32, 256, 0, stream>>>(xh, Wh + (size_t)N_LAYERS * 4096, b_enc,
                                          dis, batch, GhA, pooled, N, 0);

    for (int l = 0; l < N_LAYERS; ++l) {
        int last = (l == N_LAYERS - 1);
        k_gather<<<(N + 3) / 4, 256, 0, stream>>>(csr_src, rowptr, dis, GhA, AGGh, N);
        k_gemm_mfma<<<gb32, 256, 0, stream>>>(AGGh, Wh + (size_t)l * 4096,
                                              b_conv + (size_t)l * HIDDEN, dis, batch,
                                              GhA, pooled, N, last ? 2 : 1);
    }

    k_readout<<<(N_GRAPHS * N_CLASSES + 255) / 256, 256, 0, stream>>>(pooled, W_out, b_out, out);
}

// Round 15
// 402.345 us; speedup vs baseline: 1.7034x; 1.0543x over previous
//
#include <hip/hip_runtime.h>
#include <math.h>

#define HIDDEN 64
#define N_LAYERS 4
#define N_CLASSES 10
#define N_GRAPHS 512
#define BSH 8                        // coarse bucket: 256 nodes
#define NPB 256                      // nodes per bucket
#define PART_K 2048                  // edges per partition block

typedef _Float16 __h;
typedef __attribute__((ext_vector_type(4))) _Float16 half4;   // 8 B
typedef __attribute__((ext_vector_type(8))) _Float16 half8;   // 16 B, MFMA A/B frag
typedef __attribute__((ext_vector_type(4))) float f32x4;      // MFMA acc

// ---------------- pass 1: global bucket histogram ----------------
__global__ __launch_bounds__(256) void k_histA(const int* __restrict__ dst,
                                               int* __restrict__ ghist, int E, int NB) {
    __shared__ int hist[512];
    int t = threadIdx.x;
    hist[t] = 0; hist[t + 256] = 0;
    __syncthreads();
    int base = blockIdx.x * PART_K;
    int kend = min(PART_K, E - base);
    for (int k = t; k < kend; k += 256) atomicAdd(&hist[dst[base + k] >> BSH], 1);
    __syncthreads();
    for (int j = t; j < NB; j += 256) {
        int h = hist[j];
        if (h) atomicAdd(&ghist[j], h);
    }
}

// ---------------- pass 2: scan bucket sizes -> bases, init cursors ----------------
__global__ __launch_bounds__(256) void k_bucketscan(const int* __restrict__ ghist,
                                                    int* __restrict__ bucketbase,
                                                    int* __restrict__ gcur, int NB) {
    __shared__ int s[256];
    int t = threadIdx.x;
    int j0 = 2 * t, j1 = 2 * t + 1;
    int h0 = (j0 < NB) ? ghist[j0] : 0;
    int h1 = (j1 < NB) ? ghist[j1] : 0;
    s[t] = h0 + h1; __syncthreads();
    for (int o = 1; o < 256; o <<= 1) {
        int x = (t >= o) ? s[t - o] : 0;
        __syncthreads();
        s[t] += x;
        __syncthreads();
    }
    int base = (t == 0) ? 0 : s[t - 1];
    if (j0 <= NB) { bucketbase[j0] = base;      gcur[j0] = base; }
    if (j1 <= NB) { bucketbase[j1] = base + h0; gcur[j1] = base + h0; }
}

// ---------------- pass 3: partition edges into bucket segments (LDS reorder) ----------------
__global__ __launch_bounds__(256) void k_partition(const int* __restrict__ src,
                                                   const int* __restrict__ dst,
                                                   int* __restrict__ gcur,
                                                   int* __restrict__ packed,
                                                   int E, int NB) {
    __shared__ int hist[512];
    __shared__ int scanE[512];
    __shared__ int cur[512];
    __shared__ int delta[512];
    __shared__ int ps[256];
    __shared__ int stage[PART_K];
    int t = threadIdx.x;
    int base = blockIdx.x * PART_K;
    int kend = min(PART_K, E - base);

    hist[t] = 0; hist[t + 256] = 0;
    __syncthreads();
    for (int k = t; k < kend; k += 256) atomicAdd(&hist[dst[base + k] >> BSH], 1);
    __syncthreads();

    int j0 = 2 * t, j1 = j0 + 1;
    int h0 = hist[j0], h1 = hist[j1];
    ps[t] = h0 + h1; __syncthreads();
    for (int o = 1; o < 256; o <<= 1) {
        int x = (t >= o) ? ps[t - o] : 0;
        __syncthreads();
        ps[t] += x;
        __syncthreads();
    }
    int bexc = (t == 0) ? 0 : ps[t - 1];
    scanE[j0] = bexc;
    scanE[j1] = bexc + h0;
    __syncthreads();

    for (int j = t; j < NB; j += 256) {
        int h = hist[j];
        int g = h ? atomicAdd(&gcur[j], h) : 0;
        delta[j] = g - scanE[j];
        cur[j]   = scanE[j];
    }
    __syncthreads();

    for (int k = t; k < kend; k += 256) {
        int d = dst[base + k], s = src[base + k];
        int j = d >> BSH;
        int pos = atomicAdd(&cur[j], 1);
        stage[pos] = (s << BSH) | (d & (NPB - 1));
    }
    __syncthreads();

    for (int i = t; i < kend; i += 256) {
        int lo = 0, hi = NB;
        while (hi - lo > 1) {
            int mid = (lo + hi) >> 1;
            if (scanE[mid] <= i) lo = mid; else hi = mid;
        }
        packed[i + delta[lo]] = stage[i];
    }
}

// ---------------- pass 4: per-bucket CSR fill; emits rowptr + dis ----------------
__global__ __launch_bounds__(256) void k_fill3(const int* __restrict__ packed,
                                               const int* __restrict__ bucketbase,
                                               int* __restrict__ rowptr,
                                               float* __restrict__ dis,
                                               int* __restrict__ csr_src,
                                               int N, int E) {
    __shared__ int cnt[256];
    __shared__ int rp[256];
    int j = blockIdx.x;
    int t = threadIdx.x;
    int node0 = j << BSH;
    int segb = bucketbase[j];
    int sege = bucketbase[j + 1];

    cnt[t] = 0; __syncthreads();
    for (int i = segb + t; i < sege; i += 256) atomicAdd(&cnt[packed[i] & (NPB - 1)], 1);
    __syncthreads();

    int c = cnt[t];
    rp[t] = c; __syncthreads();
    for (int o = 1; o < 256; o <<= 1) {
        int x = (t >= o) ? rp[t - o] : 0;
        __syncthreads();
        rp[t] += x;
        __syncthreads();
    }
    int start = segb + rp[t] - c;
    int node = node0 + t;
    if (node < N) {
        rowptr[node] = start;
        dis[node] = rsqrtf((float)c + 1.0f);
        if (node == N - 1) rowptr[N] = E;
    }
    __syncthreads();
    cnt[t] = start;
    __syncthreads();
    for (int i = segb + t; i < sege; i += 256) {
        int v = packed[i];
        int slot = atomicAdd(&cnt[v & (NPB - 1)], 1);
        csr_src[slot] = v >> BSH;
    }
}

// ---------------- fp16 helpers ----------------
__device__ __forceinline__ half4 shfl_xor_h4(half4 v, int m) {
    uint2 u = __builtin_bit_cast(uint2, v);
    u.x = __shfl_xor((int)u.x, m);
    u.y = __shfl_xor((int)u.y, m);
    return __builtin_bit_cast(half4, u);
}

// ---------------- prep: W_conv (l=0..3) + W_enc (l=4) -> fp16 B-fragment layout ----------------
__global__ __launch_bounds__(256) void k_prepW(const float* __restrict__ Wconv,
                                               const float* __restrict__ Wenc,
                                               __h* __restrict__ Wh) {
    int idx = blockIdx.x * 256 + threadIdx.x;        // l*4096 + k*64 + n
    int l = idx >> 12;
    int kn = idx & 4095;
    int k = kn >> 6, n = kn & 63;
    int nt = n >> 4, nl = n & 15;
    int kt = k >> 5, kr = k & 31;
    int quad = kr >> 3, j = kr & 7;
    int lane = quad * 16 + nl;
    int pos = (((nt * 2 + kt) * 64 + lane) << 3) + j;
    float w = (l < N_LAYERS) ? Wconv[(size_t)l * 4096 + kn] : Wenc[kn];
    Wh[(l << 12) + pos] = (__h)w;
}

// ---------------- gather: AGG[d] = fp16( dis[d] * (G[d] + sum G[src]) ) ----------------
// one wave per node; 4 edge-groups x 16 lanes x 8B(half4); 4-edge unroll -> 16 rows in flight.
__global__ __launch_bounds__(256) void k_gather(const int* __restrict__ csr_src,
                                                const int* __restrict__ rowptr,
                                                const float* __restrict__ dis,
                                                const __h* __restrict__ G,
                                                __h* __restrict__ AGG, int N) {
    int node = blockIdx.x * 4 + (threadIdx.x >> 6);
    if (node >= N) return;
    int lane = threadIdx.x & 63;
    int grp  = lane >> 4;      // 0..3 edge groups
    int f4   = lane & 15;      // 8-byte (4 fp16) chunk of the 128-B row
    int beg  = rowptr[node];
    int end  = rowptr[node + 1];

    const half4 z = {(__h)0.f, (__h)0.f, (__h)0.f, (__h)0.f};
    half4 a = z;
    int e = beg + grp;
    while (e < end) {
        int s0 = csr_src[e];
        int s1 = (e + 4  < end) ? csr_src[e + 4]  : -1;
        int s2 = (e + 8  < end) ? csr_src[e + 8]  : -1;
        int s3 = (e + 12 < end) ? csr_src[e + 12] : -1;
        half4 r0 = ((const half4*)(G + (size_t)s0 * 64))[f4];
        half4 r1 = (s1 >= 0) ? ((const half4*)(G + (size_t)s1 * 64))[f4] : z;
        half4 r2 = (s2 >= 0) ? ((const half4*)(G + (size_t)s2 * 64))[f4] : z;
        half4 r3 = (s3 >= 0) ? ((const half4*)(G + (size_t)s3 * 64))[f4] : z;
        a += r0; a += r1; a += r2; a += r3;
        e += 16;
    }
    a += shfl_xor_h4(a, 16);
    a += shfl_xor_h4(a, 32);

    if (grp == 0) {
        half4 self = ((const half4*)(G + (size_t)node * 64))[f4];
        __h dd = (__h)dis[node];
        half4 o = (a + self) * dd;
        ((half4*)(AGG + (size_t)node * 64))[f4] = o;
    }
}

// ---------------- MFMA GEMM: [N,64] @ [64,64]fp16, 32 rows/wave ----------------
// mode 0 (enc):  input is fp32 (xf), converted in-register;  Gho = fp16( dis * (v + b) )
// mode 1 (mid):  input fp16;  Gho = fp16( dis * silu(v + b) )
// mode 2 (last): input fp16;  pooled[batch] += silu(v + b)
__global__ __launch_bounds__(256) void k_gemm_mfma(const __h* __restrict__ in,
                                                   const float* __restrict__ xf,
                                                   const __h* __restrict__ Wh,
                                                   const float* __restrict__ bias,
                                                   const float* __restrict__ dis,
                                                   const int* __restrict__ batch,
                                                   __h* __restrict__ Gho,
                                                   float* __restrict__ pooled,
                                                   int N, int mode) {
    int wave = threadIdx.x >> 6;
    int lane = threadIdx.x & 63;
    int row0 = (blockIdx.x * 4 + wave) * 32;
    if (row0 >= N) return;
    int quad = lane >> 4, nl = lane & 15;

    half8 bf[4][2];
    #pragma unroll
    for (int nt = 0; nt < 4; ++nt)
        #pragma unroll
        for (int kt = 0; kt < 2; ++kt)
            bf[nt][kt] = *(const half8*)(Wh + (((nt * 2 + kt) * 64 + lane) << 3));

    f32x4 acc[2][4];
    #pragma unroll
    for (int h = 0; h < 2; ++h) {
        int r = row0 + h * 16 + nl; if (r >= N) r = N - 1;
        half8 a0, a1;
        if (mode == 0) {
            const float* ap = xf + (size_t)r * 64 + quad * 8;
            float4 v0 = ((const float4*)ap)[0];
            float4 v1 = ((const float4*)ap)[1];
            float4 v2 = ((const float4*)(ap + 32))[0];
            float4 v3 = ((const float4*)(ap + 32))[1];
            a0 = (half8){(__h)v0.x, (__h)v0.y, (__h)v0.z, (__h)v0.w,
                         (__h)v1.x, (__h)v1.y, (__h)v1.z, (__h)v1.w};
            a1 = (half8){(__h)v2.x, (__h)v2.y, (__h)v2.z, (__h)v2.w,
                         (__h)v3.x, (__h)v3.y, (__h)v3.z, (__h)v3.w};
        } else {
            const __h* ap = in + (size_t)r * 64 + quad * 8;
            a0 = *(const half8*)(ap);
            a1 = *(const half8*)(ap + 32);
        }
        #pragma unroll
        for (int nt = 0; nt < 4; ++nt) {
            acc[h][nt] = (f32x4){0.f, 0.f, 0.f, 0.f};
            acc[h][nt] = __builtin_amdgcn_mfma_f32_16x16x32_f16(a0, bf[nt][0], acc[h][nt], 0, 0, 0);
            acc[h][nt] = __builtin_amdgcn_mfma_f32_16x16x32_f16(a1, bf[nt][1], acc[h][nt], 0, 0, 0);
        }
    }

    float b[4];
    #pragma unroll
    for (int nt = 0; nt < 4; ++nt) b[nt] = bias[nt * 16 + nl];

    if (mode != 2) {
        #pragma unroll
        for (int h = 0; h < 2; ++h) {
            #pragma unroll
            for (int reg = 0; reg < 4; ++reg) {
                int rr = row0 + h * 16 + quad * 4 + reg;
                if (rr < N) {
                    float ds = dis[rr];
                    #pragma unroll
                    for (int nt = 0; nt < 4; ++nt) {
                        float v = acc[h][nt][reg] + b[nt];
                        if (mode == 1) v = v / (1.0f + expf(-v));
                        Gho[(size_t)rr * 64 + nt * 16 + nl] = (__h)(ds * v);
                    }
                }
            }
        }
    } else {
        float run[4] = {0.f, 0.f, 0.f, 0.f};
        int cur = -1;
        #pragma unroll
        for (int h = 0; h < 2; ++h) {
            #pragma unroll
            for (int reg = 0; reg < 4; ++reg) {
                int rr = row0 + h * 16 + quad * 4 + reg;
                if (rr < N) {
                    int bi = batch[rr];
                    float vals[4];
                    #pragma unroll
                    for (int nt = 0; nt < 4; ++nt) {
                        float v = acc[h][nt][reg] + b[nt];
                        vals[nt] = v / (1.0f + expf(-v));
                    }
                    if (bi != cur) {
                        if (cur >= 0) {
                            #pragma unroll
                            for (int nt = 0; nt < 4; ++nt)
                                atomicAdd(&pooled[cur * 64 + nt * 16 + nl], run[nt]);
                        }
                        cur = bi;
                        #pragma unroll
                        for (int nt = 0; nt < 4; ++nt) run[nt] = vals[nt];
                    } else {
                        #pragma unroll
                        for (int nt = 0; nt < 4; ++nt) run[nt] += vals[nt];
                    }
                }
            }
        }
        if (cur >= 0) {
            #pragma unroll
            for (int nt = 0; nt < 4; ++nt)
                atomicAdd(&pooled[cur * 64 + nt * 16 + nl], run[nt]);
        }
    }
}

// ---------------- readout ----------------
__global__ __launch_bounds__(256) void k_readout(const float* __restrict__ pooled,
                                                 const float* __restrict__ Wout,
                                                 const float* __restrict__ bout,
                                                 float* __restrict__ out) {
    int idx = blockIdx.x * 256 + threadIdx.x;
    if (idx >= N_GRAPHS * N_CLASSES) return;
    int g = idx / N_CLASSES, c = idx % N_CLASSES;
    float s = bout[c];
    #pragma unroll
    for (int j = 0; j < 64; ++j) s += pooled[g * 64 + j] * Wout[j * N_CLASSES + c];
    out[idx] = fmaxf(s, 0.0f);
}

extern "C" void kernel_launch(void* const* d_in, const int* in_sizes, int n_in,
                              void* d_out, int out_size, void* d_ws, size_t ws_size,
                              hipStream_t stream) {
    const float* x      = (const float*)d_in[0];
    const int*   ei     = (const int*)d_in[1];
    const int*   batch  = (const int*)d_in[2];
    const float* W_enc  = (const float*)d_in[3];
    const float* b_enc  = (const float*)d_in[4];
    const float* W_conv = (const float*)d_in[5];
    const float* b_conv = (const float*)d_in[6];
    const float* W_out  = (const float*)d_in[7];
    const float* b_out  = (const float*)d_in[8];
    float* out = (float*)d_out;

    const int N = in_sizes[2];
    const int E = in_sizes[1] / 2;
    const int* src = ei;
    const int* dst = ei + E;
    const int NB   = (N + NPB - 1) >> BSH;
    const int NBLK = (E + PART_K - 1) / PART_K;

    char* ws = (char*)d_ws;
    size_t off = 0;
    auto alloc = [&](size_t bytes) -> char* {
        char* p = ws + off;
        off += (bytes + 255) & ~(size_t)255;
        return p;
    };
    int*   ghist      = (int*)alloc((size_t)(NB + 1) * sizeof(int));
    int*   bucketbase = (int*)alloc((size_t)(NB + 1) * sizeof(int));
    int*   gcur       = (int*)alloc((size_t)(NB + 1) * sizeof(int));
    int*   packed     = (int*)alloc((size_t)E * sizeof(int));
    int*   csr_src    = (int*)alloc((size_t)E * sizeof(int));
    int*   rowptr     = (int*)alloc((size_t)(N + 1) * sizeof(int));
    float* dis        = (float*)alloc((size_t)N * sizeof(float));
    __h*   GhA        = (__h*)alloc((size_t)N * HIDDEN * sizeof(__h));
    __h*   AGGh       = (__h*)alloc((size_t)N * HIDDEN * sizeof(__h));
    __h*   Wh         = (__h*)alloc((size_t)(N_LAYERS + 1) * 4096 * sizeof(__h));
    float* pooled     = (float*)alloc((size_t)N_GRAPHS * HIDDEN * sizeof(float));
    (void)ws_size;

    hipMemsetAsync(ghist, 0, (size_t)(NB + 1) * sizeof(int), stream);
    hipMemsetAsync(pooled, 0, (size_t)N_GRAPHS * HIDDEN * sizeof(float), stream);

    k_histA     <<<NBLK, 256, 0, stream>>>(dst, ghist, E, NB);
    k_bucketscan<<<1,    256, 0, stream>>>(ghist, bucketbase, gcur, NB);
    k_partition <<<NBLK, 256, 0, stream>>>(src, dst, gcur, packed, E, NB);
    k_fill3     <<<NB,   256, 0, stream>>>(packed, bucketbase, rowptr, dis, csr_src, N, E);
    k_prepW<<<((N_LAYERS + 1) * 4096) / 256, 256, 0, stream>>>(W_conv, W_enc, Wh);

    int gb32 = (N + 127) / 128;   // 32 rows/wave, 4 waves/block
    // encoder: GhA = fp16(dis * (x @ W_enc + b_enc)) — reads fp32 x directly
    k_gemm_mfma<<<gb32, 256, 0, stream>>>(nullptr, x, Wh + (size_t)N_LAYERS * 4096, b_enc,
                                          dis, batch, GhA, pooled, N, 0);

    for (int l = 0; l < N_LAYERS; ++l) {
        int last = (l == N_LAYERS - 1);
        k_gather<<<(N + 3) / 4, 256, 0, stream>>>(csr_src, rowptr, dis, GhA, AGGh, N);
        k_gemm_mfma<<<gb32, 256, 0, stream>>>(AGGh, nullptr, Wh + (size_t)l * 4096,
                                              b_conv + (size_t)l * HIDDEN, dis, batch,
                                              GhA, pooled, N, last ? 2 : 1);
    }

    k_readout<<<(N_GRAPHS * N_CLASSES + 255) / 256, 256, 0, stream>>>(pooled, W_out, b_out, out);
}

// Round 16
// 386.120 us; speedup vs baseline: 1.7750x; 1.0420x over previous
//
#include <hip/hip_runtime.h>
#include <math.h>

#define HIDDEN 64
#define N_LAYERS 4
#define N_CLASSES 10
#define N_GRAPHS 512
#define BSH 8                        // coarse bucket: 256 nodes
#define NPB 256                      // nodes per bucket
#define PART_K 2048                  // edges per partition block

typedef _Float16 __h;
typedef __attribute__((ext_vector_type(4))) _Float16 half4;   // 8 B
typedef __attribute__((ext_vector_type(8))) _Float16 half8;   // 16 B, MFMA A/B frag
typedef __attribute__((ext_vector_type(4))) float f32x4;      // MFMA acc

// ---------------- pass 1: global bucket histogram ----------------
__global__ __launch_bounds__(256) void k_histA(const int* __restrict__ dst,
                                               int* __restrict__ ghist, int E, int NB) {
    __shared__ int hist[512];
    int t = threadIdx.x;
    hist[t] = 0; hist[t + 256] = 0;
    __syncthreads();
    int base = blockIdx.x * PART_K;
    int kend = min(PART_K, E - base);
    for (int k = t; k < kend; k += 256) atomicAdd(&hist[dst[base + k] >> BSH], 1);
    __syncthreads();
    for (int j = t; j < NB; j += 256) {
        int h = hist[j];
        if (h) atomicAdd(&ghist[j], h);
    }
}

// ---------------- pass 2: scan bucket sizes -> bases, init cursors ----------------
__global__ __launch_bounds__(256) void k_bucketscan(const int* __restrict__ ghist,
                                                    int* __restrict__ bucketbase,
                                                    int* __restrict__ gcur, int NB) {
    __shared__ int s[256];
    int t = threadIdx.x;
    int j0 = 2 * t, j1 = 2 * t + 1;
    int h0 = (j0 < NB) ? ghist[j0] : 0;
    int h1 = (j1 < NB) ? ghist[j1] : 0;
    s[t] = h0 + h1; __syncthreads();
    for (int o = 1; o < 256; o <<= 1) {
        int x = (t >= o) ? s[t - o] : 0;
        __syncthreads();
        s[t] += x;
        __syncthreads();
    }
    int base = (t == 0) ? 0 : s[t - 1];
    if (j0 <= NB) { bucketbase[j0] = base;      gcur[j0] = base; }
    if (j1 <= NB) { bucketbase[j1] = base + h0; gcur[j1] = base + h0; }
}

// ---------------- pass 3: partition edges into bucket segments (LDS reorder) ----------------
__global__ __launch_bounds__(256) void k_partition(const int* __restrict__ src,
                                                   const int* __restrict__ dst,
                                                   int* __restrict__ gcur,
                                                   int* __restrict__ packed,
                                                   int E, int NB) {
    __shared__ int hist[512];
    __shared__ int scanE[512];
    __shared__ int cur[512];
    __shared__ int delta[512];
    __shared__ int ps[256];
    __shared__ int stage[PART_K];
    int t = threadIdx.x;
    int base = blockIdx.x * PART_K;
    int kend = min(PART_K, E - base);

    hist[t] = 0; hist[t + 256] = 0;
    __syncthreads();
    for (int k = t; k < kend; k += 256) atomicAdd(&hist[dst[base + k] >> BSH], 1);
    __syncthreads();

    int j0 = 2 * t, j1 = j0 + 1;
    int h0 = hist[j0], h1 = hist[j1];
    ps[t] = h0 + h1; __syncthreads();
    for (int o = 1; o < 256; o <<= 1) {
        int x = (t >= o) ? ps[t - o] : 0;
        __syncthreads();
        ps[t] += x;
        __syncthreads();
    }
    int bexc = (t == 0) ? 0 : ps[t - 1];
    scanE[j0] = bexc;
    scanE[j1] = bexc + h0;
    __syncthreads();

    for (int j = t; j < NB; j += 256) {
        int h = hist[j];
        int g = h ? atomicAdd(&gcur[j], h) : 0;
        delta[j] = g - scanE[j];
        cur[j]   = scanE[j];
    }
    __syncthreads();

    for (int k = t; k < kend; k += 256) {
        int d = dst[base + k], s = src[base + k];
        int j = d >> BSH;
        int pos = atomicAdd(&cur[j], 1);
        stage[pos] = (s << BSH) | (d & (NPB - 1));
    }
    __syncthreads();

    for (int i = t; i < kend; i += 256) {
        int lo = 0, hi = NB;
        while (hi - lo > 1) {
            int mid = (lo + hi) >> 1;
            if (scanE[mid] <= i) lo = mid; else hi = mid;
        }
        packed[i + delta[lo]] = stage[i];
    }
}

// ---------------- pass 4: per-bucket CSR fill with SELF-EDGE prepend ----------------
// csr gets E+N entries: each node's segment = [self, edges...].
// csr_start(node) = packed_start(node) + node   (each prior node adds exactly 1 self)
__global__ __launch_bounds__(256) void k_fill3(const int* __restrict__ packed,
                                               const int* __restrict__ bucketbase,
                                               int* __restrict__ rowptr,
                                               float* __restrict__ dis,
                                               int* __restrict__ csr_src,
                                               int N, int E) {
    __shared__ int cnt[256];
    __shared__ int rp[256];
    int j = blockIdx.x;
    int t = threadIdx.x;
    int node0 = j << BSH;
    int segb = bucketbase[j];       // packed (real-edge) base
    int sege = bucketbase[j + 1];

    cnt[t] = 0; __syncthreads();
    for (int i = segb + t; i < sege; i += 256) atomicAdd(&cnt[packed[i] & (NPB - 1)], 1);
    __syncthreads();

    int c = cnt[t];
    rp[t] = c; __syncthreads();
    for (int o = 1; o < 256; o <<= 1) {
        int x = (t >= o) ? rp[t - o] : 0;
        __syncthreads();
        rp[t] += x;
        __syncthreads();
    }
    int node = node0 + t;
    int start = segb + rp[t] - c + node;   // + node = selves before this node
    if (node < N) {
        rowptr[node] = start;
        dis[node] = rsqrtf((float)c + 1.0f);
        csr_src[start] = node;             // self edge first
        if (node == N - 1) rowptr[N] = E + N;
    }
    __syncthreads();
    cnt[t] = start + 1;                    // cursor after the self slot
    __syncthreads();
    for (int i = segb + t; i < sege; i += 256) {
        int v = packed[i];
        int slot = atomicAdd(&cnt[v & (NPB - 1)], 1);
        csr_src[slot] = v >> BSH;
    }
}

// ---------------- fp16 helpers ----------------
__device__ __forceinline__ half4 shfl_xor_h4(half4 v, int m) {
    uint2 u = __builtin_bit_cast(uint2, v);
    u.x = __shfl_xor((int)u.x, m);
    u.y = __shfl_xor((int)u.y, m);
    return __builtin_bit_cast(half4, u);
}

// ---------------- prep: W_conv (l=0..3) + W_enc (l=4) -> fp16 B-fragment layout ----------------
__global__ __launch_bounds__(256) void k_prepW(const float* __restrict__ Wconv,
                                               const float* __restrict__ Wenc,
                                               __h* __restrict__ Wh) {
    int idx = blockIdx.x * 256 + threadIdx.x;        // l*4096 + k*64 + n
    int l = idx >> 12;
    int kn = idx & 4095;
    int k = kn >> 6, n = kn & 63;
    int nt = n >> 4, nl = n & 15;
    int kt = k >> 5, kr = k & 31;
    int quad = kr >> 3, j = kr & 7;
    int lane = quad * 16 + nl;
    int pos = (((nt * 2 + kt) * 64 + lane) << 3) + j;
    float w = (l < N_LAYERS) ? Wconv[(size_t)l * 4096 + kn] : Wenc[kn];
    Wh[(l << 12) + pos] = (__h)w;
}

// ---------------- gather: AGG[d] = fp16( dis[d] * sum_{e in seg(d)} G[csr[e]] ) ----------------
// self edge is already in the segment. One wave per node; 4 groups x 16 lanes x 8B;
// 8-slot unroll -> up to 32 row-loads in flight per wave.
__global__ __launch_bounds__(256) void k_gather(const int* __restrict__ csr_src,
                                                const int* __restrict__ rowptr,
                                                const float* __restrict__ dis,
                                                const __h* __restrict__ G,
                                                __h* __restrict__ AGG, int N) {
    int node = blockIdx.x * 4 + (threadIdx.x >> 6);
    if (node >= N) return;
    int lane = threadIdx.x & 63;
    int grp  = lane >> 4;      // 0..3 edge groups
    int f4   = lane & 15;      // 8-byte (4 fp16) chunk of the 128-B row
    int beg  = rowptr[node];
    int end  = rowptr[node + 1];

    const half4 z = {(__h)0.f, (__h)0.f, (__h)0.f, (__h)0.f};
    half4 a = z;
    int e = beg + grp;
    while (e < end) {
        int s0 = csr_src[e];
        int s1 = (e + 4  < end) ? csr_src[e + 4]  : -1;
        int s2 = (e + 8  < end) ? csr_src[e + 8]  : -1;
        int s3 = (e + 12 < end) ? csr_src[e + 12] : -1;
        int s4 = (e + 16 < end) ? csr_src[e + 16] : -1;
        int s5 = (e + 20 < end) ? csr_src[e + 20] : -1;
        int s6 = (e + 24 < end) ? csr_src[e + 24] : -1;
        int s7 = (e + 28 < end) ? csr_src[e + 28] : -1;
        half4 r0 = ((const half4*)(G + (size_t)s0 * 64))[f4];
        half4 r1 = (s1 >= 0) ? ((const half4*)(G + (size_t)s1 * 64))[f4] : z;
        half4 r2 = (s2 >= 0) ? ((const half4*)(G + (size_t)s2 * 64))[f4] : z;
        half4 r3 = (s3 >= 0) ? ((const half4*)(G + (size_t)s3 * 64))[f4] : z;
        half4 r4 = (s4 >= 0) ? ((const half4*)(G + (size_t)s4 * 64))[f4] : z;
        half4 r5 = (s5 >= 0) ? ((const half4*)(G + (size_t)s5 * 64))[f4] : z;
        half4 r6 = (s6 >= 0) ? ((const half4*)(G + (size_t)s6 * 64))[f4] : z;
        half4 r7 = (s7 >= 0) ? ((const half4*)(G + (size_t)s7 * 64))[f4] : z;
        a += r0; a += r1; a += r2; a += r3;
        a += r4; a += r5; a += r6; a += r7;
        e += 32;
    }
    a += shfl_xor_h4(a, 16);
    a += shfl_xor_h4(a, 32);

    if (grp == 0) {
        __h dd = (__h)dis[node];
        half4 o = a * dd;
        ((half4*)(AGG + (size_t)node * 64))[f4] = o;
    }
}

// ---------------- MFMA GEMM: [N,64] @ [64,64]fp16, 32 rows/wave ----------------
// mode 0 (enc):  input is fp32 (xf), converted in-register;  Gho = fp16( dis * (v + b) )
// mode 1 (mid):  input fp16;  Gho = fp16( dis * silu(v + b) )
// mode 2 (last): input fp16;  pooled[batch] += silu(v + b)
__global__ __launch_bounds__(256) void k_gemm_mfma(const __h* __restrict__ in,
                                                   const float* __restrict__ xf,
                                                   const __h* __restrict__ Wh,
                                                   const float* __restrict__ bias,
                                                   const float* __restrict__ dis,
                                                   const int* __restrict__ batch,
                                                   __h* __restrict__ Gho,
                                                   float* __restrict__ pooled,
                                                   int N, int mode) {
    int wave = threadIdx.x >> 6;
    int lane = threadIdx.x & 63;
    int row0 = (blockIdx.x * 4 + wave) * 32;
    if (row0 >= N) return;
    int quad = lane >> 4, nl = lane & 15;

    half8 bf[4][2];
    #pragma unroll
    for (int nt = 0; nt < 4; ++nt)
        #pragma unroll
        for (int kt = 0; kt < 2; ++kt)
            bf[nt][kt] = *(const half8*)(Wh + (((nt * 2 + kt) * 64 + lane) << 3));

    f32x4 acc[2][4];
    #pragma unroll
    for (int h = 0; h < 2; ++h) {
        int r = row0 + h * 16 + nl; if (r >= N) r = N - 1;
        half8 a0, a1;
        if (mode == 0) {
            const float* ap = xf + (size_t)r * 64 + quad * 8;
            float4 v0 = ((const float4*)ap)[0];
            float4 v1 = ((const float4*)ap)[1];
            float4 v2 = ((const float4*)(ap + 32))[0];
            float4 v3 = ((const float4*)(ap + 32))[1];
            a0 = (half8){(__h)v0.x, (__h)v0.y, (__h)v0.z, (__h)v0.w,
                         (__h)v1.x, (__h)v1.y, (__h)v1.z, (__h)v1.w};
            a1 = (half8){(__h)v2.x, (__h)v2.y, (__h)v2.z, (__h)v2.w,
                         (__h)v3.x, (__h)v3.y, (__h)v3.z, (__h)v3.w};
        } else {
            const __h* ap = in + (size_t)r * 64 + quad * 8;
            a0 = *(const half8*)(ap);
            a1 = *(const half8*)(ap + 32);
        }
        #pragma unroll
        for (int nt = 0; nt < 4; ++nt) {
            acc[h][nt] = (f32x4){0.f, 0.f, 0.f, 0.f};
            acc[h][nt] = __builtin_amdgcn_mfma_f32_16x16x32_f16(a0, bf[nt][0], acc[h][nt], 0, 0, 0);
            acc[h][nt] = __builtin_amdgcn_mfma_f32_16x16x32_f16(a1, bf[nt][1], acc[h][nt], 0, 0, 0);
        }
    }

    float b[4];
    #pragma unroll
    for (int nt = 0; nt < 4; ++nt) b[nt] = bias[nt * 16 + nl];

    if (mode != 2) {
        #pragma unroll
        for (int h = 0; h < 2; ++h) {
            #pragma unroll
            for (int reg = 0; reg < 4; ++reg) {
                int rr = row0 + h * 16 + quad * 4 + reg;
                if (rr < N) {
                    float ds = dis[rr];
                    #pragma unroll
                    for (int nt = 0; nt < 4; ++nt) {
                        float v = acc[h][nt][reg] + b[nt];
                        if (mode == 1) v = v / (1.0f + expf(-v));
                        Gho[(size_t)rr * 64 + nt * 16 + nl] = (__h)(ds * v);
                    }
                }
            }
        }
    } else {
        float run[4] = {0.f, 0.f, 0.f, 0.f};
        int cur = -1;
        #pragma unroll
        for (int h = 0; h < 2; ++h) {
            #pragma unroll
            for (int reg = 0; reg < 4; ++reg) {
                int rr = row0 + h * 16 + quad * 4 + reg;
                if (rr < N) {
                    int bi = batch[rr];
                    float vals[4];
                    #pragma unroll
                    for (int nt = 0; nt < 4; ++nt) {
                        float v = acc[h][nt][reg] + b[nt];
                        vals[nt] = v / (1.0f + expf(-v));
                    }
                    if (bi != cur) {
                        if (cur >= 0) {
                            #pragma unroll
                            for (int nt = 0; nt < 4; ++nt)
                                atomicAdd(&pooled[cur * 64 + nt * 16 + nl], run[nt]);
                        }
                        cur = bi;
                        #pragma unroll
                        for (int nt = 0; nt < 4; ++nt) run[nt] = vals[nt];
                    } else {
                        #pragma unroll
                        for (int nt = 0; nt < 4; ++nt) run[nt] += vals[nt];
                    }
                }
            }
        }
        if (cur >= 0) {
            #pragma unroll
            for (int nt = 0; nt < 4; ++nt)
                atomicAdd(&pooled[cur * 64 + nt * 16 + nl], run[nt]);
        }
    }
}

// ---------------- readout ----------------
__global__ __launch_bounds__(256) void k_readout(const float* __restrict__ pooled,
                                                 const float* __restrict__ Wout,
                                                 const float* __restrict__ bout,
                                                 float* __restrict__ out) {
    int idx = blockIdx.x * 256 + threadIdx.x;
    if (idx >= N_GRAPHS * N_CLASSES) return;
    int g = idx / N_CLASSES, c = idx % N_CLASSES;
    float s = bout[c];
    #pragma unroll
    for (int j = 0; j < 64; ++j) s += pooled[g * 64 + j] * Wout[j * N_CLASSES + c];
    out[idx] = fmaxf(s, 0.0f);
}

extern "C" void kernel_launch(void* const* d_in, const int* in_sizes, int n_in,
                              void* d_out, int out_size, void* d_ws, size_t ws_size,
                              hipStream_t stream) {
    const float* x      = (const float*)d_in[0];
    const int*   ei     = (const int*)d_in[1];
    const int*   batch  = (const int*)d_in[2];
    const float* W_enc  = (const float*)d_in[3];
    const float* b_enc  = (const float*)d_in[4];
    const float* W_conv = (const float*)d_in[5];
    const float* b_conv = (const float*)d_in[6];
    const float* W_out  = (const float*)d_in[7];
    const float* b_out  = (const float*)d_in[8];
    float* out = (float*)d_out;

    const int N = in_sizes[2];
    const int E = in_sizes[1] / 2;
    const int* src = ei;
    const int* dst = ei + E;
    const int NB   = (N + NPB - 1) >> BSH;
    const int NBLK = (E + PART_K - 1) / PART_K;

    char* ws = (char*)d_ws;
    size_t off = 0;
    auto alloc = [&](size_t bytes) -> char* {
        char* p = ws + off;
        off += (bytes + 255) & ~(size_t)255;
        return p;
    };
    int*   ghist      = (int*)alloc((size_t)(NB + 1) * sizeof(int));
    int*   bucketbase = (int*)alloc((size_t)(NB + 1) * sizeof(int));
    int*   gcur       = (int*)alloc((size_t)(NB + 1) * sizeof(int));
    int*   packed     = (int*)alloc((size_t)E * sizeof(int));
    int*   csr_src    = (int*)alloc((size_t)(E + N) * sizeof(int));
    int*   rowptr     = (int*)alloc((size_t)(N + 1) * sizeof(int));
    float* dis        = (float*)alloc((size_t)N * sizeof(float));
    __h*   GhA        = (__h*)alloc((size_t)N * HIDDEN * sizeof(__h));
    __h*   AGGh       = (__h*)alloc((size_t)N * HIDDEN * sizeof(__h));
    __h*   Wh         = (__h*)alloc((size_t)(N_LAYERS + 1) * 4096 * sizeof(__h));
    float* pooled     = (float*)alloc((size_t)N_GRAPHS * HIDDEN * sizeof(float));
    (void)ws_size;

    hipMemsetAsync(ghist, 0, (size_t)(NB + 1) * sizeof(int), stream);
    hipMemsetAsync(pooled, 0, (size_t)N_GRAPHS * HIDDEN * sizeof(float), stream);

    k_histA     <<<NBLK, 256, 0, stream>>>(dst, ghist, E, NB);
    k_bucketscan<<<1,    256, 0, stream>>>(ghist, bucketbase, gcur, NB);
    k_partition <<<NBLK, 256, 0, stream>>>(src, dst, gcur, packed, E, NB);
    k_fill3     <<<NB,   256, 0, stream>>>(packed, bucketbase, rowptr, dis, csr_src, N, E);
    k_prepW<<<((N_LAYERS + 1) * 4096) / 256, 256, 0, stream>>>(W_conv, W_enc, Wh);

    int gb32 = (N + 127) / 128;   // 32 rows/wave, 4 waves/block
    // encoder: GhA = fp16(dis * (x @ W_enc + b_enc)) — reads fp32 x directly
    k_gemm_mfma<<<gb32, 256, 0, stream>>>(nullptr, x, Wh + (size_t)N_LAYERS * 4096, b_enc,
                                          dis, batch, GhA, pooled, N, 0);

    for (int l = 0; l < N_LAYERS; ++l) {
        int last = (l == N_LAYERS - 1);
        k_gather<<<(N + 3) / 4, 256, 0, stream>>>(csr_src, rowptr, dis, GhA, AGGh, N);
        k_gemm_mfma<<<gb32, 256, 0, stream>>>(AGGh, nullptr, Wh + (size_t)l * 4096,
                                              b_conv + (size_t)l * HIDDEN, dis, batch,
                                              GhA, pooled, N, last ? 2 : 1);
    }

    k_readout<<<(N_GRAPHS * N_CLASSES + 255) / 256, 256, 0, stream>>>(pooled, W_out, b_out, out);
}